// Round 5
// baseline (245.309 us; speedup 1.0000x reference)
//
#include <hip/hip_runtime.h>
#include <cstddef>

// Problem constants
#define Bsz 2
#define Lr  2048
#define Dr  1024
#define Nr  16
#define M_ROWS (Bsz*Lr)          // 4096
#define NPAD   1088              // padded (W_dt | W_B | W_C | zeros), 17 tiles of 64
#define CHUNK  32
#define NCH    (Lr/CHUNK)        // 64

#define BK 32
#define NK (Dr/BK)               // 32 K-iterations

typedef __attribute__((ext_vector_type(8))) __bf16 bf16x8;
typedef __attribute__((ext_vector_type(4))) float floatx4;

__device__ __forceinline__ unsigned short f2bf(float f) {
    unsigned u = __float_as_uint(f);
    u += 0x7fffu + ((u >> 16) & 1u);
    return (unsigned short)(u >> 16);
}

__device__ __forceinline__ float bf2f(unsigned short u) {
    return __uint_as_float(((unsigned)u) << 16);
}

__device__ __forceinline__ float softplus_f(float x) {
    if (x > 0.f) return x + log1pf(__expf(-x));
    return log1pf(__expf(x));
}

// ---------------- K0: fused LayerNorm (blocks 0..4095) + weight-pack (rest) ----------------
__global__ __launch_bounds__(256) void ln_pack_kernel(const float* __restrict__ x,
                                                      const float* __restrict__ gamma,
                                                      const float* __restrict__ beta,
                                                      unsigned short* __restrict__ xnb,
                                                      const float* __restrict__ Wdt,
                                                      const float* __restrict__ WB,
                                                      const float* __restrict__ WC,
                                                      unsigned short* __restrict__ Wcat) {
    if (blockIdx.x >= M_ROWS) {
        int i = (blockIdx.x - M_ROWS) * 256 + threadIdx.x;  // over NPAD*Dr
        int row = i >> 10;
        int col = i & 1023;
        float v;
        if (row < Dr)                 v = Wdt[i];
        else if (row < Dr + Nr)       v = WB[(row - Dr) * Dr + col];
        else if (row < Dr + 2*Nr)     v = WC[(row - Dr - Nr) * Dr + col];
        else                          v = 0.f;
        Wcat[i] = f2bf(v);
        return;
    }
    int row = blockIdx.x;
    int tid = threadIdx.x;
    const float4* xr = (const float4*)(x + (size_t)row * Dr);
    float4 v = xr[tid];
    float s  = v.x + v.y + v.z + v.w;
    float ss = v.x*v.x + v.y*v.y + v.z*v.z + v.w*v.w;
    #pragma unroll
    for (int off = 32; off > 0; off >>= 1) {
        s  += __shfl_down(s, off);
        ss += __shfl_down(ss, off);
    }
    __shared__ float red[8];
    int wid = tid >> 6;
    if ((tid & 63) == 0) { red[wid*2] = s; red[wid*2+1] = ss; }
    __syncthreads();
    if (tid == 0) {
        float S = 0.f, SS = 0.f;
        #pragma unroll
        for (int w = 0; w < 4; w++) { S += red[w*2]; SS += red[w*2+1]; }
        float mu  = S * (1.f/Dr);
        float var = SS * (1.f/Dr) - mu*mu;
        red[0] = mu;
        red[1] = rsqrtf(var + 1e-5f);
    }
    __syncthreads();
    float mu = red[0], rs = red[1];
    float4 g = ((const float4*)gamma)[tid], bt = ((const float4*)beta)[tid];
    float4 o;
    o.x = (v.x - mu) * rs * g.x + bt.x;
    o.y = (v.y - mu) * rs * g.y + bt.y;
    o.z = (v.z - mu) * rs * g.z + bt.z;
    o.w = (v.w - mu) * rs * g.w + bt.w;
    ushort4 ob;
    ob.x = f2bf(o.x); ob.y = f2bf(o.y); ob.z = f2bf(o.z); ob.w = f2bf(o.w);
    ((ushort4*)(xnb + (size_t)row * Dr))[tid] = ob;
}

// ---------------- K2: MFMA GEMM [M_ROWS x NPAD] = xnb @ Wcat^T ----------------
// No-LDS register pipeline: each wave owns a private 64x64 tile (4x4 acc of
// 16x16x32 bf16), loads its 8 fragments/iter straight from global (L2-resident
// A/B), depth-3 reg buffering (loads for k+2 issued before k's MFMAs -> ~2
// iters of latency coverage). No barriers, no LDS -> the R3 LDS-pipe bound
// (24 wave-LDS ops vs 77 cyc MFMA per iter) and all bank conflicts vanish.
__global__ __launch_bounds__(256) void gemm_kernel(const unsigned short* __restrict__ xnb,
                                                   const unsigned short* __restrict__ w,
                                                   const float* __restrict__ b_dt,
                                                   float* __restrict__ dt,
                                                   float* __restrict__ bin,
                                                   float* __restrict__ cin) {
    int tid  = threadIdx.x;
    int wave = tid >> 6;
    int lane = tid & 63;
    int lm   = lane & 15;
    int quad = lane >> 4;
    int wid  = blockIdx.x * 4 + wave;   // 1088 waves
    int mt   = wid & 63;                // 64 M-tiles
    int nt   = wid >> 6;                // 17 N-tiles
    int Mb = mt * 64;
    int Nb = nt * 64;

    const unsigned short* Ap[4];
    const unsigned short* Bp[4];
    #pragma unroll
    for (int i = 0; i < 4; i++) {
        Ap[i] = xnb + (size_t)(Mb + i * 16 + lm) * Dr + quad * 8;
        Bp[i] = w   + (size_t)(Nb + i * 16 + lm) * Dr + quad * 8;
    }

    bf16x8 a[3][4], b[3][4];
    #pragma unroll
    for (int s = 0; s < 2; s++) {
        #pragma unroll
        for (int i = 0; i < 4; i++) {
            a[s][i] = *(const bf16x8*)(Ap[i] + s * BK);
            b[s][i] = *(const bf16x8*)(Bp[i] + s * BK);
        }
    }

    floatx4 acc[4][4] = {};

    #pragma unroll
    for (int kp = 0; kp < NK; kp++) {
        int cur = kp % 3;
        int nxt = (kp + 2) % 3;
        int kf  = (kp + 2 < NK) ? (kp + 2) : 0;   // clamped dummy prefetch on last 2 iters
        #pragma unroll
        for (int i = 0; i < 4; i++) {
            a[nxt][i] = *(const bf16x8*)(Ap[i] + kf * BK);
            b[nxt][i] = *(const bf16x8*)(Bp[i] + kf * BK);
        }
        #pragma unroll
        for (int i = 0; i < 4; i++)
            #pragma unroll
            for (int j = 0; j < 4; j++)
                acc[i][j] = __builtin_amdgcn_mfma_f32_16x16x32_bf16(a[cur][i], b[cur][j], acc[i][j], 0, 0, 0);
    }

    // C/D layout: col = lane&15, row = (lane>>4)*4 + reg   [m89/m91]
    #pragma unroll
    for (int i = 0; i < 4; i++) {
        int grow0 = Mb + i * 16 + quad * 4;
        #pragma unroll
        for (int j = 0; j < 4; j++) {
            int gcol = Nb + j * 16 + lm;
            #pragma unroll
            for (int r = 0; r < 4; r++) {
                float v = acc[i][j][r];
                int row = grow0 + r;
                if (gcol < Dr) {
                    dt[(size_t)row * Dr + gcol] = softplus_f(v + b_dt[gcol]);
                } else if (gcol < Dr + Nr) {
                    bin[(size_t)row * Nr + (gcol - Dr)] = v;
                } else if (gcol < Dr + 2*Nr) {
                    cin[(size_t)row * Nr + (gcol - Dr - Nr)] = v;
                }
            }
        }
    }
}

// ---------------- K3: scan pass 1 (per-chunk local scan; emit P, h_end) ----------------
__global__ __launch_bounds__(256) void scan1_kernel(const float* __restrict__ dt,
                                                    const unsigned short* __restrict__ xnb,
                                                    const float* __restrict__ bin,
                                                    const float* __restrict__ A_log,
                                                    float* __restrict__ Pws,
                                                    float* __restrict__ hendws) {
    int d  = blockIdx.x * 256 + threadIdx.x;
    int ch = blockIdx.y;
    int b  = blockIdx.z;
    int l0 = ch * CHUNK;
    size_t rowbase = (size_t)b * Lr + l0;

    float ac[16];
    #pragma unroll
    for (int i = 0; i < 4; i++) {
        float4 t = ((const float4*)(A_log + (size_t)d * Nr))[i];
        ac[i*4+0] = -__expf(t.x);
        ac[i*4+1] = -__expf(t.y);
        ac[i*4+2] = -__expf(t.z);
        ac[i*4+3] = -__expf(t.w);
    }

    __shared__ float lb[CHUNK * Nr];
    for (int i = threadIdx.x; i < CHUNK * Nr; i += 256)
        lb[i] = bin[rowbase * Nr + i];
    __syncthreads();

    float h[16];
    #pragma unroll
    for (int n = 0; n < 16; n++) h[n] = 0.f;
    float S = 0.f;

    const float* dtp          = dt  + rowbase * Dr + d;
    const unsigned short* xp  = xnb + rowbase * Dr + d;

    for (int t = 0; t < CHUNK; t++) {
        float dtv = dtp[t * Dr];
        float xv  = bf2f(xp[t * Dr]);
        S += dtv;
        float cm = dtv * xv;
        const float* br = lb + t * Nr;
        float4 b0 = *(const float4*)(br);
        float4 b1 = *(const float4*)(br + 4);
        float4 b2 = *(const float4*)(br + 8);
        float4 b3 = *(const float4*)(br + 12);
        h[0]  = __expf(dtv*ac[0])  * h[0]  + cm * b0.x;
        h[1]  = __expf(dtv*ac[1])  * h[1]  + cm * b0.y;
        h[2]  = __expf(dtv*ac[2])  * h[2]  + cm * b0.z;
        h[3]  = __expf(dtv*ac[3])  * h[3]  + cm * b0.w;
        h[4]  = __expf(dtv*ac[4])  * h[4]  + cm * b1.x;
        h[5]  = __expf(dtv*ac[5])  * h[5]  + cm * b1.y;
        h[6]  = __expf(dtv*ac[6])  * h[6]  + cm * b1.z;
        h[7]  = __expf(dtv*ac[7])  * h[7]  + cm * b1.w;
        h[8]  = __expf(dtv*ac[8])  * h[8]  + cm * b2.x;
        h[9]  = __expf(dtv*ac[9])  * h[9]  + cm * b2.y;
        h[10] = __expf(dtv*ac[10]) * h[10] + cm * b2.z;
        h[11] = __expf(dtv*ac[11]) * h[11] + cm * b2.w;
        h[12] = __expf(dtv*ac[12]) * h[12] + cm * b3.x;
        h[13] = __expf(dtv*ac[13]) * h[13] + cm * b3.y;
        h[14] = __expf(dtv*ac[14]) * h[14] + cm * b3.z;
        h[15] = __expf(dtv*ac[15]) * h[15] + cm * b3.w;
    }

    size_t obase = (((size_t)(b * NCH + ch)) * Dr + d) * Nr;
    #pragma unroll
    for (int i = 0; i < 4; i++) {
        float4 p, he;
        p.x = __expf(S*ac[i*4+0]); p.y = __expf(S*ac[i*4+1]);
        p.z = __expf(S*ac[i*4+2]); p.w = __expf(S*ac[i*4+3]);
        he.x = h[i*4+0]; he.y = h[i*4+1]; he.z = h[i*4+2]; he.w = h[i*4+3];
        ((float4*)(Pws   + obase))[i] = p;
        ((float4*)(hendws + obase))[i] = he;
    }
}

// ---------------- K4: combine chunk states sequentially ----------------
__global__ __launch_bounds__(256) void combine_kernel(const float* __restrict__ Pws,
                                                      const float* __restrict__ hendws,
                                                      float* __restrict__ hinws) {
    int id = blockIdx.x * 256 + threadIdx.x;  // B*D*N = 32768
    int b  = id >> 14;
    int dn = id & 16383;
    size_t base = ((size_t)b * NCH) * (Dr * Nr) + dn;
    float hin = 0.f;
    #pragma unroll 4
    for (int c = 0; c < NCH; c++) {
        size_t idx = base + (size_t)c * (Dr * Nr);
        float p = Pws[idx];
        float he = hendws[idx];
        hinws[idx] = hin;
        hin = p * hin + he;
    }
}

// ---------------- K5: scan pass 2 (re-scan with h_in; emit y + D*residual) ----------------
__global__ __launch_bounds__(256) void scan2_kernel(const float* __restrict__ dt,
                                                    const unsigned short* __restrict__ xnb,
                                                    const float* __restrict__ bin,
                                                    const float* __restrict__ cin,
                                                    const float* __restrict__ A_log,
                                                    const float* __restrict__ hinws,
                                                    const float* __restrict__ x,
                                                    const float* __restrict__ Dp,
                                                    float* __restrict__ out) {
    int d  = blockIdx.x * 256 + threadIdx.x;
    int ch = blockIdx.y;
    int b  = blockIdx.z;
    int l0 = ch * CHUNK;
    size_t rowbase = (size_t)b * Lr + l0;

    float ac[16];
    #pragma unroll
    for (int i = 0; i < 4; i++) {
        float4 t = ((const float4*)(A_log + (size_t)d * Nr))[i];
        ac[i*4+0] = -__expf(t.x);
        ac[i*4+1] = -__expf(t.y);
        ac[i*4+2] = -__expf(t.z);
        ac[i*4+3] = -__expf(t.w);
    }

    __shared__ float lb[CHUNK * Nr];
    __shared__ float lc[CHUNK * Nr];
    for (int i = threadIdx.x; i < CHUNK * Nr; i += 256) {
        lb[i] = bin[rowbase * Nr + i];
        lc[i] = cin[rowbase * Nr + i];
    }
    __syncthreads();

    size_t obase = (((size_t)(b * NCH + ch)) * Dr + d) * Nr;
    float h[16];
    #pragma unroll
    for (int i = 0; i < 4; i++) {
        float4 hv = ((const float4*)(hinws + obase))[i];
        h[i*4+0] = hv.x; h[i*4+1] = hv.y; h[i*4+2] = hv.z; h[i*4+3] = hv.w;
    }

    float dp = Dp[d];
    const float* dtp         = dt  + rowbase * Dr + d;
    const unsigned short* xp = xnb + rowbase * Dr + d;
    const float* xr          = x   + rowbase * Dr + d;
    float* op                = out + rowbase * Dr + d;

    for (int t = 0; t < CHUNK; t++) {
        float dtv = dtp[t * Dr];
        float xv  = bf2f(xp[t * Dr]);
        float cm = dtv * xv;
        const float* br = lb + t * Nr;
        const float* cr = lc + t * Nr;
        float4 b0 = *(const float4*)(br);
        float4 b1 = *(const float4*)(br + 4);
        float4 b2 = *(const float4*)(br + 8);
        float4 b3 = *(const float4*)(br + 12);
        float4 c0 = *(const float4*)(cr);
        float4 c1 = *(const float4*)(cr + 4);
        float4 c2 = *(const float4*)(cr + 8);
        float4 c3 = *(const float4*)(cr + 12);
        float y = 0.f;
        h[0]  = __expf(dtv*ac[0])  * h[0]  + cm * b0.x;  y += c0.x * h[0];
        h[1]  = __expf(dtv*ac[1])  * h[1]  + cm * b0.y;  y += c0.y * h[1];
        h[2]  = __expf(dtv*ac[2])  * h[2]  + cm * b0.z;  y += c0.z * h[2];
        h[3]  = __expf(dtv*ac[3])  * h[3]  + cm * b0.w;  y += c0.w * h[3];
        h[4]  = __expf(dtv*ac[4])  * h[4]  + cm * b1.x;  y += c1.x * h[4];
        h[5]  = __expf(dtv*ac[5])  * h[5]  + cm * b1.y;  y += c1.y * h[5];
        h[6]  = __expf(dtv*ac[6])  * h[6]  + cm * b1.z;  y += c1.z * h[6];
        h[7]  = __expf(dtv*ac[7])  * h[7]  + cm * b1.w;  y += c1.w * h[7];
        h[8]  = __expf(dtv*ac[8])  * h[8]  + cm * b2.x;  y += c2.x * h[8];
        h[9]  = __expf(dtv*ac[9])  * h[9]  + cm * b2.y;  y += c2.y * h[9];
        h[10] = __expf(dtv*ac[10]) * h[10] + cm * b2.z;  y += c2.z * h[10];
        h[11] = __expf(dtv*ac[11]) * h[11] + cm * b2.w;  y += c2.w * h[11];
        h[12] = __expf(dtv*ac[12]) * h[12] + cm * b3.x;  y += c3.x * h[12];
        h[13] = __expf(dtv*ac[13]) * h[13] + cm * b3.y;  y += c3.y * h[13];
        h[14] = __expf(dtv*ac[14]) * h[14] + cm * b3.z;  y += c3.z * h[14];
        h[15] = __expf(dtv*ac[15]) * h[15] + cm * b3.w;  y += c3.w * h[15];
        op[t * Dr] = y + dp * xr[t * Dr];
    }
}

// ---------------- host ----------------
extern "C" void kernel_launch(void* const* d_in, const int* in_sizes, int n_in,
                              void* d_out, int out_size, void* d_ws, size_t ws_size,
                              hipStream_t stream) {
    const float* x      = (const float*)d_in[0];
    const float* W_dt   = (const float*)d_in[1];
    const float* b_dt   = (const float*)d_in[2];
    const float* W_B    = (const float*)d_in[3];
    const float* W_C    = (const float*)d_in[4];
    const float* Dparam = (const float*)d_in[5];
    const float* A_log  = (const float*)d_in[6];
    const float* gamma  = (const float*)d_in[7];
    const float* beta   = (const float*)d_in[8];
    float* out = (float*)d_out;

    char* ws = (char*)d_ws;
    unsigned short* xnb  = (unsigned short*)(ws);                     // 8 MB
    unsigned short* wcat = (unsigned short*)(ws + 8388608);           // 2.125 MB
    float*          dt   = (float*)(ws + 10616832);                   // 16 MB
    float*          bin  = (float*)(ws + 27394048);                   // 256 KB
    float*          cin  = (float*)(ws + 27656192);                   // 256 KB
    float*          Pws  = (float*)(ws + 27918336);                   // 8 MB
    float*          hend = (float*)(ws + 36306944);                   // 8 MB
    float*          hin  = (float*)(ws + 44695552);                   // 8 MB  (total ~53 MB)

    ln_pack_kernel<<<M_ROWS + (NPAD * Dr) / 256, 256, 0, stream>>>(
        x, gamma, beta, xnb, W_dt, W_B, W_C, wcat);
    gemm_kernel<<<(M_ROWS / 64) * (NPAD / 64) / 4, 256, 0, stream>>>(xnb, wcat, b_dt, dt, bin, cin);
    dim3 sgrid(Dr / 256, NCH, Bsz);
    scan1_kernel<<<sgrid, 256, 0, stream>>>(dt, xnb, bin, A_log, Pws, hend);
    combine_kernel<<<(Bsz * Dr * Nr) / 256, 256, 0, stream>>>(Pws, hend, hin);
    scan2_kernel<<<sgrid, 256, 0, stream>>>(dt, xnb, bin, cin, A_log, hin, x, Dparam, out);
}

// Round 6
// 205.756 us; speedup vs baseline: 1.1922x; 1.1922x over previous
//
#include <hip/hip_runtime.h>
#include <cstddef>

// Problem constants
#define Bsz 2
#define Lr  2048
#define Dr  1024
#define Nr  16
#define M_ROWS (Bsz*Lr)          // 4096
#define NPAD   1088              // padded (W_dt | W_B | W_C | zeros), 17 tiles of 64
#define CHUNK  32
#define NCH    (Lr/CHUNK)        // 64

#define BK 32
#define NK (Dr/BK)               // 32 K-iterations

typedef __attribute__((ext_vector_type(8))) __bf16 bf16x8;
typedef __attribute__((ext_vector_type(4))) float floatx4;

__device__ __forceinline__ unsigned short f2bf(float f) {
    unsigned u = __float_as_uint(f);
    u += 0x7fffu + ((u >> 16) & 1u);
    return (unsigned short)(u >> 16);
}

__device__ __forceinline__ float bf2f(unsigned short u) {
    return __uint_as_float(((unsigned)u) << 16);
}

__device__ __forceinline__ float softplus_f(float x) {
    // abs threshold is 0.905 -> fast log is fine
    if (x > 0.f) return x + __logf(1.f + __expf(-x));
    return __logf(1.f + __expf(x));
}

// ---------------- K0: fused LayerNorm (blocks 0..4095) + weight-pack (rest) ----------------
__global__ __launch_bounds__(256) void ln_pack_kernel(const float* __restrict__ x,
                                                      const float* __restrict__ gamma,
                                                      const float* __restrict__ beta,
                                                      unsigned short* __restrict__ xnb,
                                                      const float* __restrict__ Wdt,
                                                      const float* __restrict__ WB,
                                                      const float* __restrict__ WC,
                                                      unsigned short* __restrict__ Wcat) {
    if (blockIdx.x >= M_ROWS) {
        int i = (blockIdx.x - M_ROWS) * 256 + threadIdx.x;  // over NPAD*Dr
        int row = i >> 10;
        int col = i & 1023;
        float v;
        if (row < Dr)                 v = Wdt[i];
        else if (row < Dr + Nr)       v = WB[(row - Dr) * Dr + col];
        else if (row < Dr + 2*Nr)     v = WC[(row - Dr - Nr) * Dr + col];
        else                          v = 0.f;
        Wcat[i] = f2bf(v);
        return;
    }
    int row = blockIdx.x;
    int tid = threadIdx.x;
    const float4* xr = (const float4*)(x + (size_t)row * Dr);
    float4 v = xr[tid];
    float s  = v.x + v.y + v.z + v.w;
    float ss = v.x*v.x + v.y*v.y + v.z*v.z + v.w*v.w;
    #pragma unroll
    for (int off = 32; off > 0; off >>= 1) {
        s  += __shfl_down(s, off);
        ss += __shfl_down(ss, off);
    }
    __shared__ float red[8];
    int wid = tid >> 6;
    if ((tid & 63) == 0) { red[wid*2] = s; red[wid*2+1] = ss; }
    __syncthreads();
    if (tid == 0) {
        float S = 0.f, SS = 0.f;
        #pragma unroll
        for (int w = 0; w < 4; w++) { S += red[w*2]; SS += red[w*2+1]; }
        float mu  = S * (1.f/Dr);
        float var = SS * (1.f/Dr) - mu*mu;
        red[0] = mu;
        red[1] = rsqrtf(var + 1e-5f);
    }
    __syncthreads();
    float mu = red[0], rs = red[1];
    float4 g = ((const float4*)gamma)[tid], bt = ((const float4*)beta)[tid];
    float4 o;
    o.x = (v.x - mu) * rs * g.x + bt.x;
    o.y = (v.y - mu) * rs * g.y + bt.y;
    o.z = (v.z - mu) * rs * g.z + bt.z;
    o.w = (v.w - mu) * rs * g.w + bt.w;
    ushort4 ob;
    ob.x = f2bf(o.x); ob.y = f2bf(o.y); ob.z = f2bf(o.z); ob.w = f2bf(o.w);
    ((ushort4*)(xnb + (size_t)row * Dr))[tid] = ob;
}

// ---------------- K2: MFMA GEMM [M_ROWS x NPAD] = xnb @ Wcat^T ----------------
// No-LDS, 1 wave per block (64 thr), 64x64 tile per wave, depth-3 register
// pipeline (loads for k+2 in flight while computing k). R5's version of this
// died because the compiler's occupancy heuristic allocated only 84 VGPRs and
// rematerialized the pipeline into just-in-time loads; __launch_bounds__(64,2)
// raises the cap to 256 so the ~180-reg pipeline survives. 1088 even blocks
// (vs 272 lumpy 4-wave ones) spread the work 1 wave/SIMD-ish across all CUs.
__global__ __launch_bounds__(64, 2) void gemm_kernel(const unsigned short* __restrict__ xnb,
                                                     const unsigned short* __restrict__ w,
                                                     const float* __restrict__ b_dt,
                                                     float* __restrict__ dt,
                                                     float* __restrict__ bin,
                                                     float* __restrict__ cin) {
    int lane = threadIdx.x;
    int lm   = lane & 15;
    int quad = lane >> 4;
    int bid  = blockIdx.x;              // 1088 blocks
    int mt   = bid / 17;                // 64 M-tiles (17 consecutive blocks share A-tile)
    int nt   = bid % 17;                // 17 N-tiles
    int Mb = mt * 64;
    int Nb = nt * 64;

    const unsigned short* Ap[4];
    const unsigned short* Bp[4];
    #pragma unroll
    for (int i = 0; i < 4; i++) {
        Ap[i] = xnb + (size_t)(Mb + i * 16 + lm) * Dr + quad * 8;
        Bp[i] = w   + (size_t)(Nb + i * 16 + lm) * Dr + quad * 8;
    }

    bf16x8 a[3][4], b[3][4];
    #pragma unroll
    for (int s = 0; s < 2; s++) {
        #pragma unroll
        for (int i = 0; i < 4; i++) {
            a[s][i] = *(const bf16x8*)(Ap[i] + s * BK);
            b[s][i] = *(const bf16x8*)(Bp[i] + s * BK);
        }
    }

    floatx4 acc[4][4] = {};

    #pragma unroll
    for (int kp = 0; kp < NK; kp++) {
        int cur = kp % 3;
        int nxt = (kp + 2) % 3;
        int kf  = (kp + 2) & 31;   // wraps to 0/1 on last 2 iters: dummy in-bounds prefetch
        #pragma unroll
        for (int i = 0; i < 4; i++) {
            a[nxt][i] = *(const bf16x8*)(Ap[i] + kf * BK);
            b[nxt][i] = *(const bf16x8*)(Bp[i] + kf * BK);
        }
        #pragma unroll
        for (int i = 0; i < 4; i++)
            #pragma unroll
            for (int j = 0; j < 4; j++)
                acc[i][j] = __builtin_amdgcn_mfma_f32_16x16x32_bf16(a[cur][i], b[cur][j], acc[i][j], 0, 0, 0);
    }

    // C/D layout: col = lane&15, row = (lane>>4)*4 + reg   [m89/m91]
    #pragma unroll
    for (int i = 0; i < 4; i++) {
        int grow0 = Mb + i * 16 + quad * 4;
        #pragma unroll
        for (int j = 0; j < 4; j++) {
            int gcol = Nb + j * 16 + lm;
            #pragma unroll
            for (int r = 0; r < 4; r++) {
                float v = acc[i][j][r];
                int row = grow0 + r;
                if (gcol < Dr) {
                    dt[(size_t)row * Dr + gcol] = softplus_f(v + b_dt[gcol]);
                } else if (gcol < Dr + Nr) {
                    bin[(size_t)row * Nr + (gcol - Dr)] = v;
                } else if (gcol < Dr + 2*Nr) {
                    cin[(size_t)row * Nr + (gcol - Dr - Nr)] = v;
                }
            }
        }
    }
}

// ---------------- K3: scan pass 1 (per-chunk local scan; emit P, h_end) ----------------
__global__ __launch_bounds__(256) void scan1_kernel(const float* __restrict__ dt,
                                                    const unsigned short* __restrict__ xnb,
                                                    const float* __restrict__ bin,
                                                    const float* __restrict__ A_log,
                                                    float* __restrict__ Pws,
                                                    float* __restrict__ hendws) {
    int d  = blockIdx.x * 256 + threadIdx.x;
    int ch = blockIdx.y;
    int b  = blockIdx.z;
    int l0 = ch * CHUNK;
    size_t rowbase = (size_t)b * Lr + l0;

    float ac[16];
    #pragma unroll
    for (int i = 0; i < 4; i++) {
        float4 t = ((const float4*)(A_log + (size_t)d * Nr))[i];
        ac[i*4+0] = -__expf(t.x);
        ac[i*4+1] = -__expf(t.y);
        ac[i*4+2] = -__expf(t.z);
        ac[i*4+3] = -__expf(t.w);
    }

    __shared__ float lb[CHUNK * Nr];
    for (int i = threadIdx.x; i < CHUNK * Nr; i += 256)
        lb[i] = bin[rowbase * Nr + i];
    __syncthreads();

    float h[16];
    #pragma unroll
    for (int n = 0; n < 16; n++) h[n] = 0.f;
    float S = 0.f;

    const float* dtp          = dt  + rowbase * Dr + d;
    const unsigned short* xp  = xnb + rowbase * Dr + d;

    for (int tb = 0; tb < CHUNK; tb += 4) {
        // batched loads: 8 independent loads in flight (was 2 serial per iter)
        float dt4[4], xv4[4];
        #pragma unroll
        for (int u = 0; u < 4; u++) {
            dt4[u] = dtp[(tb + u) * Dr];
            xv4[u] = bf2f(xp[(tb + u) * Dr]);
        }
        #pragma unroll
        for (int u = 0; u < 4; u++) {
            float dtv = dt4[u];
            float xv  = xv4[u];
            S += dtv;
            float cm = dtv * xv;
            const float* br = lb + (tb + u) * Nr;
            float4 b0 = *(const float4*)(br);
            float4 b1 = *(const float4*)(br + 4);
            float4 b2 = *(const float4*)(br + 8);
            float4 b3 = *(const float4*)(br + 12);
            h[0]  = __expf(dtv*ac[0])  * h[0]  + cm * b0.x;
            h[1]  = __expf(dtv*ac[1])  * h[1]  + cm * b0.y;
            h[2]  = __expf(dtv*ac[2])  * h[2]  + cm * b0.z;
            h[3]  = __expf(dtv*ac[3])  * h[3]  + cm * b0.w;
            h[4]  = __expf(dtv*ac[4])  * h[4]  + cm * b1.x;
            h[5]  = __expf(dtv*ac[5])  * h[5]  + cm * b1.y;
            h[6]  = __expf(dtv*ac[6])  * h[6]  + cm * b1.z;
            h[7]  = __expf(dtv*ac[7])  * h[7]  + cm * b1.w;
            h[8]  = __expf(dtv*ac[8])  * h[8]  + cm * b2.x;
            h[9]  = __expf(dtv*ac[9])  * h[9]  + cm * b2.y;
            h[10] = __expf(dtv*ac[10]) * h[10] + cm * b2.z;
            h[11] = __expf(dtv*ac[11]) * h[11] + cm * b2.w;
            h[12] = __expf(dtv*ac[12]) * h[12] + cm * b3.x;
            h[13] = __expf(dtv*ac[13]) * h[13] + cm * b3.y;
            h[14] = __expf(dtv*ac[14]) * h[14] + cm * b3.z;
            h[15] = __expf(dtv*ac[15]) * h[15] + cm * b3.w;
        }
    }

    size_t obase = (((size_t)(b * NCH + ch)) * Dr + d) * Nr;
    #pragma unroll
    for (int i = 0; i < 4; i++) {
        float4 p, he;
        p.x = __expf(S*ac[i*4+0]); p.y = __expf(S*ac[i*4+1]);
        p.z = __expf(S*ac[i*4+2]); p.w = __expf(S*ac[i*4+3]);
        he.x = h[i*4+0]; he.y = h[i*4+1]; he.z = h[i*4+2]; he.w = h[i*4+3];
        ((float4*)(Pws   + obase))[i] = p;
        ((float4*)(hendws + obase))[i] = he;
    }
}

// ---------------- K4: combine chunk states sequentially ----------------
__global__ __launch_bounds__(256) void combine_kernel(const float* __restrict__ Pws,
                                                      const float* __restrict__ hendws,
                                                      float* __restrict__ hinws) {
    int id = blockIdx.x * 256 + threadIdx.x;  // B*D*N = 32768
    int b  = id >> 14;
    int dn = id & 16383;
    size_t base = ((size_t)b * NCH) * (Dr * Nr) + dn;
    float hin = 0.f;
    #pragma unroll 4
    for (int c = 0; c < NCH; c++) {
        size_t idx = base + (size_t)c * (Dr * Nr);
        float p = Pws[idx];
        float he = hendws[idx];
        hinws[idx] = hin;
        hin = p * hin + he;
    }
}

// ---------------- K5: scan pass 2 (re-scan with h_in; emit y + D*residual) ----------------
__global__ __launch_bounds__(256) void scan2_kernel(const float* __restrict__ dt,
                                                    const unsigned short* __restrict__ xnb,
                                                    const float* __restrict__ bin,
                                                    const float* __restrict__ cin,
                                                    const float* __restrict__ A_log,
                                                    const float* __restrict__ hinws,
                                                    const float* __restrict__ x,
                                                    const float* __restrict__ Dp,
                                                    float* __restrict__ out) {
    int d  = blockIdx.x * 256 + threadIdx.x;
    int ch = blockIdx.y;
    int b  = blockIdx.z;
    int l0 = ch * CHUNK;
    size_t rowbase = (size_t)b * Lr + l0;

    float ac[16];
    #pragma unroll
    for (int i = 0; i < 4; i++) {
        float4 t = ((const float4*)(A_log + (size_t)d * Nr))[i];
        ac[i*4+0] = -__expf(t.x);
        ac[i*4+1] = -__expf(t.y);
        ac[i*4+2] = -__expf(t.z);
        ac[i*4+3] = -__expf(t.w);
    }

    __shared__ float lb[CHUNK * Nr];
    __shared__ float lc[CHUNK * Nr];
    for (int i = threadIdx.x; i < CHUNK * Nr; i += 256) {
        lb[i] = bin[rowbase * Nr + i];
        lc[i] = cin[rowbase * Nr + i];
    }
    __syncthreads();

    size_t obase = (((size_t)(b * NCH + ch)) * Dr + d) * Nr;
    float h[16];
    #pragma unroll
    for (int i = 0; i < 4; i++) {
        float4 hv = ((const float4*)(hinws + obase))[i];
        h[i*4+0] = hv.x; h[i*4+1] = hv.y; h[i*4+2] = hv.z; h[i*4+3] = hv.w;
    }

    float dp = Dp[d];
    const float* dtp         = dt  + rowbase * Dr + d;
    const unsigned short* xp = xnb + rowbase * Dr + d;
    const float* xr          = x   + rowbase * Dr + d;
    float* op                = out + rowbase * Dr + d;

    for (int tb = 0; tb < CHUNK; tb += 4) {
        float dt4[4], xv4[4], xr4[4];
        #pragma unroll
        for (int u = 0; u < 4; u++) {
            dt4[u] = dtp[(tb + u) * Dr];
            xv4[u] = bf2f(xp[(tb + u) * Dr]);
            xr4[u] = xr[(tb + u) * Dr];
        }
        #pragma unroll
        for (int u = 0; u < 4; u++) {
            float dtv = dt4[u];
            float xv  = xv4[u];
            float cm = dtv * xv;
            const float* br = lb + (tb + u) * Nr;
            const float* cr = lc + (tb + u) * Nr;
            float4 b0 = *(const float4*)(br);
            float4 b1 = *(const float4*)(br + 4);
            float4 b2 = *(const float4*)(br + 8);
            float4 b3 = *(const float4*)(br + 12);
            float4 c0 = *(const float4*)(cr);
            float4 c1 = *(const float4*)(cr + 4);
            float4 c2 = *(const float4*)(cr + 8);
            float4 c3 = *(const float4*)(cr + 12);
            float y = 0.f;
            h[0]  = __expf(dtv*ac[0])  * h[0]  + cm * b0.x;  y += c0.x * h[0];
            h[1]  = __expf(dtv*ac[1])  * h[1]  + cm * b0.y;  y += c0.y * h[1];
            h[2]  = __expf(dtv*ac[2])  * h[2]  + cm * b0.z;  y += c0.z * h[2];
            h[3]  = __expf(dtv*ac[3])  * h[3]  + cm * b0.w;  y += c0.w * h[3];
            h[4]  = __expf(dtv*ac[4])  * h[4]  + cm * b1.x;  y += c1.x * h[4];
            h[5]  = __expf(dtv*ac[5])  * h[5]  + cm * b1.y;  y += c1.y * h[5];
            h[6]  = __expf(dtv*ac[6])  * h[6]  + cm * b1.z;  y += c1.z * h[6];
            h[7]  = __expf(dtv*ac[7])  * h[7]  + cm * b1.w;  y += c1.w * h[7];
            h[8]  = __expf(dtv*ac[8])  * h[8]  + cm * b2.x;  y += c2.x * h[8];
            h[9]  = __expf(dtv*ac[9])  * h[9]  + cm * b2.y;  y += c2.y * h[9];
            h[10] = __expf(dtv*ac[10]) * h[10] + cm * b2.z;  y += c2.z * h[10];
            h[11] = __expf(dtv*ac[11]) * h[11] + cm * b2.w;  y += c2.w * h[11];
            h[12] = __expf(dtv*ac[12]) * h[12] + cm * b3.x;  y += c3.x * h[12];
            h[13] = __expf(dtv*ac[13]) * h[13] + cm * b3.y;  y += c3.y * h[13];
            h[14] = __expf(dtv*ac[14]) * h[14] + cm * b3.z;  y += c3.z * h[14];
            h[15] = __expf(dtv*ac[15]) * h[15] + cm * b3.w;  y += c3.w * h[15];
            op[(tb + u) * Dr] = y + dp * xr4[u];
        }
    }
}

// ---------------- host ----------------
extern "C" void kernel_launch(void* const* d_in, const int* in_sizes, int n_in,
                              void* d_out, int out_size, void* d_ws, size_t ws_size,
                              hipStream_t stream) {
    const float* x      = (const float*)d_in[0];
    const float* W_dt   = (const float*)d_in[1];
    const float* b_dt   = (const float*)d_in[2];
    const float* W_B    = (const float*)d_in[3];
    const float* W_C    = (const float*)d_in[4];
    const float* Dparam = (const float*)d_in[5];
    const float* A_log  = (const float*)d_in[6];
    const float* gamma  = (const float*)d_in[7];
    const float* beta   = (const float*)d_in[8];
    float* out = (float*)d_out;

    char* ws = (char*)d_ws;
    unsigned short* xnb  = (unsigned short*)(ws);                     // 8 MB
    unsigned short* wcat = (unsigned short*)(ws + 8388608);           // 2.125 MB
    float*          dt   = (float*)(ws + 10616832);                   // 16 MB
    float*          bin  = (float*)(ws + 27394048);                   // 256 KB
    float*          cin  = (float*)(ws + 27656192);                   // 256 KB
    float*          Pws  = (float*)(ws + 27918336);                   // 8 MB
    float*          hend = (float*)(ws + 36306944);                   // 8 MB
    float*          hin  = (float*)(ws + 44695552);                   // 8 MB  (total ~53 MB)

    ln_pack_kernel<<<M_ROWS + (NPAD * Dr) / 256, 256, 0, stream>>>(
        x, gamma, beta, xnb, W_dt, W_B, W_C, wcat);
    gemm_kernel<<<(M_ROWS / 64) * (NPAD / 64), 64, 0, stream>>>(xnb, wcat, b_dt, dt, bin, cin);
    dim3 sgrid(Dr / 256, NCH, Bsz);
    scan1_kernel<<<sgrid, 256, 0, stream>>>(dt, xnb, bin, A_log, Pws, hend);
    combine_kernel<<<(Bsz * Dr * Nr) / 256, 256, 0, stream>>>(Pws, hend, hin);
    scan2_kernel<<<sgrid, 256, 0, stream>>>(dt, xnb, bin, cin, A_log, hin, x, Dparam, out);
}

// Round 7
// 184.931 us; speedup vs baseline: 1.3265x; 1.1126x over previous
//
#include <hip/hip_runtime.h>
#include <cstddef>

// Problem constants
#define Bsz 2
#define Lr  2048
#define Dr  1024
#define Nr  16
#define M_ROWS (Bsz*Lr)          // 4096
#define NPAD   1088              // padded (W_dt | W_B | W_C | zeros), 17 tiles of 64
#define CHUNK  32
#define NCH    (Lr/CHUNK)        // 64

#define BK 32
#define NK (Dr/BK)               // 32 K-iterations

typedef __attribute__((ext_vector_type(8))) __bf16 bf16x8;
typedef __attribute__((ext_vector_type(4))) float floatx4;

__device__ __forceinline__ unsigned short f2bf(float f) {
    unsigned u = __float_as_uint(f);
    u += 0x7fffu + ((u >> 16) & 1u);
    return (unsigned short)(u >> 16);
}

__device__ __forceinline__ float bf2f(unsigned short u) {
    return __uint_as_float(((unsigned)u) << 16);
}

__device__ __forceinline__ float softplus_f(float x) {
    // abs threshold is 0.905 -> fast log is fine
    if (x > 0.f) return x + __logf(1.f + __expf(-x));
    return __logf(1.f + __expf(x));
}

__device__ __forceinline__ void gload_lds16(const unsigned short* g, unsigned short* l) {
    __builtin_amdgcn_global_load_lds((const __attribute__((address_space(1))) void*)g,
                                     (__attribute__((address_space(3))) void*)l, 16, 0, 0);
}

// ---------------- K0: fused LayerNorm (blocks 0..4095) + weight-pack (rest) ----------------
__global__ __launch_bounds__(256) void ln_pack_kernel(const float* __restrict__ x,
                                                      const float* __restrict__ gamma,
                                                      const float* __restrict__ beta,
                                                      unsigned short* __restrict__ xnb,
                                                      const float* __restrict__ Wdt,
                                                      const float* __restrict__ WB,
                                                      const float* __restrict__ WC,
                                                      unsigned short* __restrict__ Wcat) {
    if (blockIdx.x >= M_ROWS) {
        int i = (blockIdx.x - M_ROWS) * 256 + threadIdx.x;  // over NPAD*Dr
        int row = i >> 10;
        int col = i & 1023;
        float v;
        if (row < Dr)                 v = Wdt[i];
        else if (row < Dr + Nr)       v = WB[(row - Dr) * Dr + col];
        else if (row < Dr + 2*Nr)     v = WC[(row - Dr - Nr) * Dr + col];
        else                          v = 0.f;
        Wcat[i] = f2bf(v);
        return;
    }
    int row = blockIdx.x;
    int tid = threadIdx.x;
    const float4* xr = (const float4*)(x + (size_t)row * Dr);
    float4 v = xr[tid];
    float s  = v.x + v.y + v.z + v.w;
    float ss = v.x*v.x + v.y*v.y + v.z*v.z + v.w*v.w;
    #pragma unroll
    for (int off = 32; off > 0; off >>= 1) {
        s  += __shfl_down(s, off);
        ss += __shfl_down(ss, off);
    }
    __shared__ float red[8];
    int wid = tid >> 6;
    if ((tid & 63) == 0) { red[wid*2] = s; red[wid*2+1] = ss; }
    __syncthreads();
    if (tid == 0) {
        float S = 0.f, SS = 0.f;
        #pragma unroll
        for (int w = 0; w < 4; w++) { S += red[w*2]; SS += red[w*2+1]; }
        float mu  = S * (1.f/Dr);
        float var = SS * (1.f/Dr) - mu*mu;
        red[0] = mu;
        red[1] = rsqrtf(var + 1e-5f);
    }
    __syncthreads();
    float mu = red[0], rs = red[1];
    float4 g = ((const float4*)gamma)[tid], bt = ((const float4*)beta)[tid];
    float4 o;
    o.x = (v.x - mu) * rs * g.x + bt.x;
    o.y = (v.y - mu) * rs * g.y + bt.y;
    o.z = (v.z - mu) * rs * g.z + bt.z;
    o.w = (v.w - mu) * rs * g.w + bt.w;
    ushort4 ob;
    ob.x = f2bf(o.x); ob.y = f2bf(o.y); ob.z = f2bf(o.z); ob.w = f2bf(o.w);
    ((ushort4*)(xnb + (size_t)row * Dr))[tid] = ob;
}

// ---------------- K2: MFMA GEMM [M_ROWS x NPAD] = xnb @ Wcat^T ----------------
// Single-wave blocks (64 thr), 64x64 tile, TRIPLE-buffered LDS via
// global_load_lds (async by construction -- the compiler cannot rematerialize
// it, unlike the R5/R6 register pipelines it kept destroying). One wave per
// block means NO __syncthreads anywhere: the m97 vmcnt(0) barrier drain is
// structurally absent. Reads of tile k wait on loads issued 2 iterations ago
// (~500 cyc coverage vs 200-900 cyc L2/HBM latency).
// XCD swizzle: mt = (j/17)*8 + (bid&7) colocates the 17 blocks sharing an
// A-tile on one XCD -> A fetched from HBM once (R6's mt=bid/17 spread them
// across all 8 XCD L2s -> 42 MB FETCH, 4x over-fetch).
__global__ __launch_bounds__(64) void gemm_kernel(const unsigned short* __restrict__ xnb,
                                                  const unsigned short* __restrict__ w,
                                                  const float* __restrict__ b_dt,
                                                  float* __restrict__ dt,
                                                  float* __restrict__ bin,
                                                  float* __restrict__ cin) {
    __shared__ unsigned short As[3][64 * BK];   // 3 x 4 KB
    __shared__ unsigned short Bs[3][64 * BK];   // 3 x 4 KB
    int t    = threadIdx.x;
    int lm   = t & 15;
    int quad = t >> 4;
    int bid  = blockIdx.x;             // 1088 blocks = 8 XCD-lanes x 136
    int xcd  = bid & 7;
    int j    = bid >> 3;               // 0..135
    int nt   = j % 17;
    int mt   = (j / 17) * 8 + xcd;     // 0..63; all nt for one mt share an XCD
    int Mb = mt * 64;
    int Nb = nt * 64;

    // staging: thread t covers rows {t>>2 + 16c}, col-chunk (t&3)*8, c=0..3
    int srow = t >> 2, scc = t & 3;
    const unsigned short* Ag = xnb + (size_t)(Mb + srow) * Dr + scc * 8;
    const unsigned short* Bg = w   + (size_t)(Nb + srow) * Dr + scc * 8;

    // prologue: tiles 0,1 -> bufs 0,1
    #pragma unroll
    for (int s = 0; s < 2; s++) {
        #pragma unroll
        for (int c = 0; c < 4; c++) {
            gload_lds16(Ag + (size_t)c * 16 * Dr + s * BK, &As[s][c * 512] + t * 8);
            gload_lds16(Bg + (size_t)c * 16 * Dr + s * BK, &Bs[s][c * 512] + t * 8);
        }
    }

    floatx4 acc[4][4] = {};

    #pragma unroll
    for (int kk = 0; kk < NK; kk++) {
        int cur = kk % 3;
        // fragments of tile kk (compiler waits vmcnt for loads issued 2 iters ago)
        bf16x8 a[4], b[4];
        #pragma unroll
        for (int i = 0; i < 4; i++) {
            a[i] = *(const bf16x8*)&As[cur][(i * 16 + lm) * BK + quad * 8];
            b[i] = *(const bf16x8*)&Bs[cur][(i * 16 + lm) * BK + quad * 8];
        }
        // issue tile kk+2 into the buffer freed by tile kk-1
        if (kk + 2 < NK) {
            int nb = (kk + 2) % 3;
            #pragma unroll
            for (int c = 0; c < 4; c++) {
                gload_lds16(Ag + (size_t)c * 16 * Dr + (kk + 2) * BK, &As[nb][c * 512] + t * 8);
                gload_lds16(Bg + (size_t)c * 16 * Dr + (kk + 2) * BK, &Bs[nb][c * 512] + t * 8);
            }
        }
        #pragma unroll
        for (int i = 0; i < 4; i++)
            #pragma unroll
            for (int jj = 0; jj < 4; jj++)
                acc[i][jj] = __builtin_amdgcn_mfma_f32_16x16x32_bf16(a[i], b[jj], acc[i][jj], 0, 0, 0);
    }

    // C/D layout: col = lane&15, row = (lane>>4)*4 + reg   [m89/m91]
    #pragma unroll
    for (int i = 0; i < 4; i++) {
        int grow0 = Mb + i * 16 + quad * 4;
        #pragma unroll
        for (int jj = 0; jj < 4; jj++) {
            int gcol = Nb + jj * 16 + lm;
            #pragma unroll
            for (int r = 0; r < 4; r++) {
                float v = acc[i][jj][r];
                int row = grow0 + r;
                if (gcol < Dr) {
                    dt[(size_t)row * Dr + gcol] = softplus_f(v + b_dt[gcol]);
                } else if (gcol < Dr + Nr) {
                    bin[(size_t)row * Nr + (gcol - Dr)] = v;
                } else if (gcol < Dr + 2*Nr) {
                    cin[(size_t)row * Nr + (gcol - Dr - Nr)] = v;
                }
            }
        }
    }
}

// ---------------- K3: scan pass 1 (per-chunk local scan; emit P, h_end) ----------------
__global__ __launch_bounds__(256) void scan1_kernel(const float* __restrict__ dt,
                                                    const unsigned short* __restrict__ xnb,
                                                    const float* __restrict__ bin,
                                                    const float* __restrict__ A_log,
                                                    float* __restrict__ Pws,
                                                    float* __restrict__ hendws) {
    int d  = blockIdx.x * 256 + threadIdx.x;
    int ch = blockIdx.y;
    int b  = blockIdx.z;
    int l0 = ch * CHUNK;
    size_t rowbase = (size_t)b * Lr + l0;

    float ac[16];
    #pragma unroll
    for (int i = 0; i < 4; i++) {
        float4 t = ((const float4*)(A_log + (size_t)d * Nr))[i];
        ac[i*4+0] = -__expf(t.x);
        ac[i*4+1] = -__expf(t.y);
        ac[i*4+2] = -__expf(t.z);
        ac[i*4+3] = -__expf(t.w);
    }

    __shared__ float lb[CHUNK * Nr];
    for (int i = threadIdx.x; i < CHUNK * Nr; i += 256)
        lb[i] = bin[rowbase * Nr + i];
    __syncthreads();

    float h[16];
    #pragma unroll
    for (int n = 0; n < 16; n++) h[n] = 0.f;
    float S = 0.f;

    const float* dtp          = dt  + rowbase * Dr + d;
    const unsigned short* xp  = xnb + rowbase * Dr + d;

    for (int tb = 0; tb < CHUNK; tb += 4) {
        float dt4[4], xv4[4];
        #pragma unroll
        for (int u = 0; u < 4; u++) {
            dt4[u] = dtp[(tb + u) * Dr];
            xv4[u] = bf2f(xp[(tb + u) * Dr]);
        }
        #pragma unroll
        for (int u = 0; u < 4; u++) {
            float dtv = dt4[u];
            float xv  = xv4[u];
            S += dtv;
            float cm = dtv * xv;
            const float* br = lb + (tb + u) * Nr;
            float4 b0 = *(const float4*)(br);
            float4 b1 = *(const float4*)(br + 4);
            float4 b2 = *(const float4*)(br + 8);
            float4 b3 = *(const float4*)(br + 12);
            h[0]  = __expf(dtv*ac[0])  * h[0]  + cm * b0.x;
            h[1]  = __expf(dtv*ac[1])  * h[1]  + cm * b0.y;
            h[2]  = __expf(dtv*ac[2])  * h[2]  + cm * b0.z;
            h[3]  = __expf(dtv*ac[3])  * h[3]  + cm * b0.w;
            h[4]  = __expf(dtv*ac[4])  * h[4]  + cm * b1.x;
            h[5]  = __expf(dtv*ac[5])  * h[5]  + cm * b1.y;
            h[6]  = __expf(dtv*ac[6])  * h[6]  + cm * b1.z;
            h[7]  = __expf(dtv*ac[7])  * h[7]  + cm * b1.w;
            h[8]  = __expf(dtv*ac[8])  * h[8]  + cm * b2.x;
            h[9]  = __expf(dtv*ac[9])  * h[9]  + cm * b2.y;
            h[10] = __expf(dtv*ac[10]) * h[10] + cm * b2.z;
            h[11] = __expf(dtv*ac[11]) * h[11] + cm * b2.w;
            h[12] = __expf(dtv*ac[12]) * h[12] + cm * b3.x;
            h[13] = __expf(dtv*ac[13]) * h[13] + cm * b3.y;
            h[14] = __expf(dtv*ac[14]) * h[14] + cm * b3.z;
            h[15] = __expf(dtv*ac[15]) * h[15] + cm * b3.w;
        }
    }

    size_t obase = (((size_t)(b * NCH + ch)) * Dr + d) * Nr;
    #pragma unroll
    for (int i = 0; i < 4; i++) {
        float4 p, he;
        p.x = __expf(S*ac[i*4+0]); p.y = __expf(S*ac[i*4+1]);
        p.z = __expf(S*ac[i*4+2]); p.w = __expf(S*ac[i*4+3]);
        he.x = h[i*4+0]; he.y = h[i*4+1]; he.z = h[i*4+2]; he.w = h[i*4+3];
        ((float4*)(Pws   + obase))[i] = p;
        ((float4*)(hendws + obase))[i] = he;
    }
}

// ---------------- K4: combine chunk states sequentially ----------------
__global__ __launch_bounds__(256) void combine_kernel(const float* __restrict__ Pws,
                                                      const float* __restrict__ hendws,
                                                      float* __restrict__ hinws) {
    int id = blockIdx.x * 256 + threadIdx.x;  // B*D*N = 32768
    int b  = id >> 14;
    int dn = id & 16383;
    size_t base = ((size_t)b * NCH) * (Dr * Nr) + dn;
    float hin = 0.f;
    #pragma unroll 4
    for (int c = 0; c < NCH; c++) {
        size_t idx = base + (size_t)c * (Dr * Nr);
        float p = Pws[idx];
        float he = hendws[idx];
        hinws[idx] = hin;
        hin = p * hin + he;
    }
}

// ---------------- K5: scan pass 2 (re-scan with h_in; emit y + D*residual) ----------------
__global__ __launch_bounds__(256) void scan2_kernel(const float* __restrict__ dt,
                                                    const unsigned short* __restrict__ xnb,
                                                    const float* __restrict__ bin,
                                                    const float* __restrict__ cin,
                                                    const float* __restrict__ A_log,
                                                    const float* __restrict__ hinws,
                                                    const float* __restrict__ x,
                                                    const float* __restrict__ Dp,
                                                    float* __restrict__ out) {
    int d  = blockIdx.x * 256 + threadIdx.x;
    int ch = blockIdx.y;
    int b  = blockIdx.z;
    int l0 = ch * CHUNK;
    size_t rowbase = (size_t)b * Lr + l0;

    float ac[16];
    #pragma unroll
    for (int i = 0; i < 4; i++) {
        float4 t = ((const float4*)(A_log + (size_t)d * Nr))[i];
        ac[i*4+0] = -__expf(t.x);
        ac[i*4+1] = -__expf(t.y);
        ac[i*4+2] = -__expf(t.z);
        ac[i*4+3] = -__expf(t.w);
    }

    __shared__ float lb[CHUNK * Nr];
    __shared__ float lc[CHUNK * Nr];
    for (int i = threadIdx.x; i < CHUNK * Nr; i += 256) {
        lb[i] = bin[rowbase * Nr + i];
        lc[i] = cin[rowbase * Nr + i];
    }
    __syncthreads();

    size_t obase = (((size_t)(b * NCH + ch)) * Dr + d) * Nr;
    float h[16];
    #pragma unroll
    for (int i = 0; i < 4; i++) {
        float4 hv = ((const float4*)(hinws + obase))[i];
        h[i*4+0] = hv.x; h[i*4+1] = hv.y; h[i*4+2] = hv.z; h[i*4+3] = hv.w;
    }

    float dp = Dp[d];
    const float* dtp         = dt  + rowbase * Dr + d;
    const unsigned short* xp = xnb + rowbase * Dr + d;
    const float* xr          = x   + rowbase * Dr + d;
    float* op                = out + rowbase * Dr + d;

    for (int tb = 0; tb < CHUNK; tb += 4) {
        float dt4[4], xv4[4], xr4[4];
        #pragma unroll
        for (int u = 0; u < 4; u++) {
            dt4[u] = dtp[(tb + u) * Dr];
            xv4[u] = bf2f(xp[(tb + u) * Dr]);
            xr4[u] = xr[(tb + u) * Dr];
        }
        #pragma unroll
        for (int u = 0; u < 4; u++) {
            float dtv = dt4[u];
            float xv  = xv4[u];
            float cm = dtv * xv;
            const float* br = lb + (tb + u) * Nr;
            const float* cr = lc + (tb + u) * Nr;
            float4 b0 = *(const float4*)(br);
            float4 b1 = *(const float4*)(br + 4);
            float4 b2 = *(const float4*)(br + 8);
            float4 b3 = *(const float4*)(br + 12);
            float4 c0 = *(const float4*)(cr);
            float4 c1 = *(const float4*)(cr + 4);
            float4 c2 = *(const float4*)(cr + 8);
            float4 c3 = *(const float4*)(cr + 12);
            float y = 0.f;
            h[0]  = __expf(dtv*ac[0])  * h[0]  + cm * b0.x;  y += c0.x * h[0];
            h[1]  = __expf(dtv*ac[1])  * h[1]  + cm * b0.y;  y += c0.y * h[1];
            h[2]  = __expf(dtv*ac[2])  * h[2]  + cm * b0.z;  y += c0.z * h[2];
            h[3]  = __expf(dtv*ac[3])  * h[3]  + cm * b0.w;  y += c0.w * h[3];
            h[4]  = __expf(dtv*ac[4])  * h[4]  + cm * b1.x;  y += c1.x * h[4];
            h[5]  = __expf(dtv*ac[5])  * h[5]  + cm * b1.y;  y += c1.y * h[5];
            h[6]  = __expf(dtv*ac[6])  * h[6]  + cm * b1.z;  y += c1.z * h[6];
            h[7]  = __expf(dtv*ac[7])  * h[7]  + cm * b1.w;  y += c1.w * h[7];
            h[8]  = __expf(dtv*ac[8])  * h[8]  + cm * b2.x;  y += c2.x * h[8];
            h[9]  = __expf(dtv*ac[9])  * h[9]  + cm * b2.y;  y += c2.y * h[9];
            h[10] = __expf(dtv*ac[10]) * h[10] + cm * b2.z;  y += c2.z * h[10];
            h[11] = __expf(dtv*ac[11]) * h[11] + cm * b2.w;  y += c2.w * h[11];
            h[12] = __expf(dtv*ac[12]) * h[12] + cm * b3.x;  y += c3.x * h[12];
            h[13] = __expf(dtv*ac[13]) * h[13] + cm * b3.y;  y += c3.y * h[13];
            h[14] = __expf(dtv*ac[14]) * h[14] + cm * b3.z;  y += c3.z * h[14];
            h[15] = __expf(dtv*ac[15]) * h[15] + cm * b3.w;  y += c3.w * h[15];
            op[(tb + u) * Dr] = y + dp * xr4[u];
        }
    }
}

// ---------------- host ----------------
extern "C" void kernel_launch(void* const* d_in, const int* in_sizes, int n_in,
                              void* d_out, int out_size, void* d_ws, size_t ws_size,
                              hipStream_t stream) {
    const float* x      = (const float*)d_in[0];
    const float* W_dt   = (const float*)d_in[1];
    const float* b_dt   = (const float*)d_in[2];
    const float* W_B    = (const float*)d_in[3];
    const float* W_C    = (const float*)d_in[4];
    const float* Dparam = (const float*)d_in[5];
    const float* A_log  = (const float*)d_in[6];
    const float* gamma  = (const float*)d_in[7];
    const float* beta   = (const float*)d_in[8];
    float* out = (float*)d_out;

    char* ws = (char*)d_ws;
    unsigned short* xnb  = (unsigned short*)(ws);                     // 8 MB
    unsigned short* wcat = (unsigned short*)(ws + 8388608);           // 2.125 MB
    float*          dt   = (float*)(ws + 10616832);                   // 16 MB
    float*          bin  = (float*)(ws + 27394048);                   // 256 KB
    float*          cin  = (float*)(ws + 27656192);                   // 256 KB
    float*          Pws  = (float*)(ws + 27918336);                   // 8 MB
    float*          hend = (float*)(ws + 36306944);                   // 8 MB
    float*          hin  = (float*)(ws + 44695552);                   // 8 MB  (total ~53 MB)

    ln_pack_kernel<<<M_ROWS + (NPAD * Dr) / 256, 256, 0, stream>>>(
        x, gamma, beta, xnb, W_dt, W_B, W_C, wcat);
    gemm_kernel<<<(M_ROWS / 64) * (NPAD / 64), 64, 0, stream>>>(xnb, wcat, b_dt, dt, bin, cin);
    dim3 sgrid(Dr / 256, NCH, Bsz);
    scan1_kernel<<<sgrid, 256, 0, stream>>>(dt, xnb, bin, A_log, Pws, hend);
    combine_kernel<<<(Bsz * Dr * Nr) / 256, 256, 0, stream>>>(Pws, hend, hin);
    scan2_kernel<<<sgrid, 256, 0, stream>>>(dt, xnb, bin, cin, A_log, hin, x, Dparam, out);
}

// Round 8
// 159.403 us; speedup vs baseline: 1.5389x; 1.1602x over previous
//
#include <hip/hip_runtime.h>
#include <cstddef>

// Problem constants
#define Bsz 2
#define Lr  2048
#define Dr  1024
#define Nr  16
#define M_ROWS (Bsz*Lr)          // 4096
#define NPAD   1088              // padded (W_dt | W_B | W_C | zeros), 17 tiles of 64
#define CHUNK  32
#define NCH    (Lr/CHUNK)        // 64

#define BM 64
#define BN 64
#define BK 32
#define NK (Dr/BK)               // 32 K-iterations

typedef __attribute__((ext_vector_type(8))) __bf16 bf16x8;
typedef __attribute__((ext_vector_type(4))) float floatx4;

__device__ __forceinline__ unsigned short f2bf(float f) {
    unsigned u = __float_as_uint(f);
    u += 0x7fffu + ((u >> 16) & 1u);
    return (unsigned short)(u >> 16);
}

__device__ __forceinline__ float bf2f(unsigned short u) {
    return __uint_as_float(((unsigned)u) << 16);
}

__device__ __forceinline__ float softplus_f(float x) {
    // abs threshold is 0.905 -> fast log is fine
    if (x > 0.f) return x + __logf(1.f + __expf(-x));
    return __logf(1.f + __expf(x));
}

__device__ __forceinline__ void gload_lds16(const unsigned short* g, unsigned short* l) {
    __builtin_amdgcn_global_load_lds((const __attribute__((address_space(1))) void*)g,
                                     (__attribute__((address_space(3))) void*)l, 16, 0, 0);
}

// ---------------- K0: fused LayerNorm (blocks 0..4095) + weight-pack (rest) ----------------
__global__ __launch_bounds__(256) void ln_pack_kernel(const float* __restrict__ x,
                                                      const float* __restrict__ gamma,
                                                      const float* __restrict__ beta,
                                                      unsigned short* __restrict__ xnb,
                                                      const float* __restrict__ Wdt,
                                                      const float* __restrict__ WB,
                                                      const float* __restrict__ WC,
                                                      unsigned short* __restrict__ Wcat) {
    if (blockIdx.x >= M_ROWS) {
        int i = (blockIdx.x - M_ROWS) * 256 + threadIdx.x;  // over NPAD*Dr
        int row = i >> 10;
        int col = i & 1023;
        float v;
        if (row < Dr)                 v = Wdt[i];
        else if (row < Dr + Nr)       v = WB[(row - Dr) * Dr + col];
        else if (row < Dr + 2*Nr)     v = WC[(row - Dr - Nr) * Dr + col];
        else                          v = 0.f;
        Wcat[i] = f2bf(v);
        return;
    }
    int row = blockIdx.x;
    int tid = threadIdx.x;
    const float4* xr = (const float4*)(x + (size_t)row * Dr);
    float4 v = xr[tid];
    float s  = v.x + v.y + v.z + v.w;
    float ss = v.x*v.x + v.y*v.y + v.z*v.z + v.w*v.w;
    #pragma unroll
    for (int off = 32; off > 0; off >>= 1) {
        s  += __shfl_down(s, off);
        ss += __shfl_down(ss, off);
    }
    __shared__ float red[8];
    int wid = tid >> 6;
    if ((tid & 63) == 0) { red[wid*2] = s; red[wid*2+1] = ss; }
    __syncthreads();
    if (tid == 0) {
        float S = 0.f, SS = 0.f;
        #pragma unroll
        for (int w = 0; w < 4; w++) { S += red[w*2]; SS += red[w*2+1]; }
        float mu  = S * (1.f/Dr);
        float var = SS * (1.f/Dr) - mu*mu;
        red[0] = mu;
        red[1] = rsqrtf(var + 1e-5f);
    }
    __syncthreads();
    float mu = red[0], rs = red[1];
    float4 g = ((const float4*)gamma)[tid], bt = ((const float4*)beta)[tid];
    float4 o;
    o.x = (v.x - mu) * rs * g.x + bt.x;
    o.y = (v.y - mu) * rs * g.y + bt.y;
    o.z = (v.z - mu) * rs * g.z + bt.z;
    o.w = (v.w - mu) * rs * g.w + bt.w;
    ushort4 ob;
    ob.x = f2bf(o.x); ob.y = f2bf(o.y); ob.z = f2bf(o.z); ob.w = f2bf(o.w);
    ((ushort4*)(xnb + (size_t)row * Dr))[tid] = ob;
}

// ---------------- K2: MFMA GEMM [M_ROWS x NPAD] = xnb @ Wcat^T ----------------
// R3 structure (4-wave 64x64, BK=32, 2-barrier, global_load_lds staging) plus:
//   - XCD swizzle (17 blocks sharing an A-tile colocated on one XCD)
//   - K-OFFSET STAGGER: block (mt,nt) starts its K sweep at koff=(mt+nt)&31.
//     Theory: R3/R4/R7 (three different pipelines) all plateau at ~49us with
//     ~3.7k cyc/iter because every block sweeps k in lockstep -> the 64 blocks
//     sharing a B-tile (17 for A) hammer the SAME 64B L2 lines each instant;
//     hot-line serialization caps staging at ~9 B/cyc/CU. Staggering makes
//     sharers touch disjoint lines at any moment.
__global__ __launch_bounds__(256) void gemm_kernel(const unsigned short* __restrict__ xnb,
                                                   const unsigned short* __restrict__ w,
                                                   const float* __restrict__ b_dt,
                                                   float* __restrict__ dt,
                                                   float* __restrict__ bin,
                                                   float* __restrict__ cin) {
    __shared__ unsigned short As[BM * BK];  // 4 KB row-major [64][32]
    __shared__ unsigned short Bs[BN * BK];  // 4 KB
    int tid  = threadIdx.x;
    int wave = tid >> 6;
    int lane = tid & 63;
    int lm   = lane & 15;
    int quad = lane >> 4;
    int bid  = blockIdx.x;             // 1088 blocks = 8 XCD-lanes x 136
    int xcd  = bid & 7;
    int j0   = bid >> 3;               // 0..135
    int nt   = j0 % 17;
    int mt   = (j0 / 17) * 8 + xcd;    // 0..63
    int Mb = mt * BM;
    int Nb = nt * BN;
    int wm = (wave >> 1) * 32;
    int wn = (wave & 1)  * 32;
    int koff = (mt + nt) & (NK - 1);

    // staging: thread t loads 16B (row t/4, col-chunk (t%4)*8)
    int srow = tid >> 2, sch = tid & 3;
    const unsigned short* Ag = xnb + (size_t)(Mb + srow) * Dr + sch * 8;
    const unsigned short* Bg = w   + (size_t)(Nb + srow) * Dr + sch * 8;
    unsigned short* Al = &As[tid * 8];
    unsigned short* Bl = &Bs[tid * 8];
    const unsigned short* Ar = &As[(wm + lm) * BK + quad * 8];
    const unsigned short* Br = &Bs[(wn + lm) * BK + quad * 8];

    floatx4 acc[2][2] = {};

    for (int kk = 0; kk < NK; kk++) {
        int k0 = ((kk + koff) & (NK - 1)) * BK;
        gload_lds16(Ag + k0, Al);
        gload_lds16(Bg + k0, Bl);
        __syncthreads();   // drains vmcnt -> LDS valid
        bf16x8 a0 = *(const bf16x8*)(Ar);
        bf16x8 a1 = *(const bf16x8*)(Ar + 16 * BK);
        bf16x8 b0 = *(const bf16x8*)(Br);
        bf16x8 b1 = *(const bf16x8*)(Br + 16 * BK);
        acc[0][0] = __builtin_amdgcn_mfma_f32_16x16x32_bf16(a0, b0, acc[0][0], 0, 0, 0);
        acc[0][1] = __builtin_amdgcn_mfma_f32_16x16x32_bf16(a0, b1, acc[0][1], 0, 0, 0);
        acc[1][0] = __builtin_amdgcn_mfma_f32_16x16x32_bf16(a1, b0, acc[1][0], 0, 0, 0);
        acc[1][1] = __builtin_amdgcn_mfma_f32_16x16x32_bf16(a1, b1, acc[1][1], 0, 0, 0);
        __syncthreads();   // before next-iter overwrite
    }

    // C/D layout: col = lane&15, row = (lane>>4)*4 + reg   [m89/m91]
    #pragma unroll
    for (int i = 0; i < 2; i++) {
        int grow0 = Mb + wm + i * 16 + quad * 4;
        #pragma unroll
        for (int jj = 0; jj < 2; jj++) {
            int gcol = Nb + wn + jj * 16 + lm;
            #pragma unroll
            for (int r = 0; r < 4; r++) {
                float v = acc[i][jj][r];
                int row = grow0 + r;
                if (gcol < Dr) {
                    dt[(size_t)row * Dr + gcol] = softplus_f(v + b_dt[gcol]);
                } else if (gcol < Dr + Nr) {
                    bin[(size_t)row * Nr + (gcol - Dr)] = v;
                } else if (gcol < Dr + 2*Nr) {
                    cin[(size_t)row * Nr + (gcol - Dr - Nr)] = v;
                }
            }
        }
    }
}

// ---------------- K3: scan pass 1 (per-chunk local scan; emit P, h_end) ----------------
// P/hend layout transposed to [b][ch][n][Dr]: stores are coalesced scalar ops
// (old [d][n] float4 writes were 16B pieces strided 64B -> 4x write scatter).
__global__ __launch_bounds__(256) void scan1_kernel(const float* __restrict__ dt,
                                                    const unsigned short* __restrict__ xnb,
                                                    const float* __restrict__ bin,
                                                    const float* __restrict__ A_log,
                                                    float* __restrict__ Pws,
                                                    float* __restrict__ hendws) {
    int d  = blockIdx.x * 256 + threadIdx.x;
    int ch = blockIdx.y;
    int b  = blockIdx.z;
    int l0 = ch * CHUNK;
    size_t rowbase = (size_t)b * Lr + l0;

    float ac[16];
    #pragma unroll
    for (int i = 0; i < 4; i++) {
        float4 t = ((const float4*)(A_log + (size_t)d * Nr))[i];
        ac[i*4+0] = -__expf(t.x);
        ac[i*4+1] = -__expf(t.y);
        ac[i*4+2] = -__expf(t.z);
        ac[i*4+3] = -__expf(t.w);
    }

    __shared__ float lb[CHUNK * Nr];
    for (int i = threadIdx.x; i < CHUNK * Nr; i += 256)
        lb[i] = bin[rowbase * Nr + i];
    __syncthreads();

    float h[16];
    #pragma unroll
    for (int n = 0; n < 16; n++) h[n] = 0.f;
    float S = 0.f;

    const float* dtp          = dt  + rowbase * Dr + d;
    const unsigned short* xp  = xnb + rowbase * Dr + d;

    for (int tb = 0; tb < CHUNK; tb += 4) {
        float dt4[4], xv4[4];
        #pragma unroll
        for (int u = 0; u < 4; u++) {
            dt4[u] = dtp[(tb + u) * Dr];
            xv4[u] = bf2f(xp[(tb + u) * Dr]);
        }
        #pragma unroll
        for (int u = 0; u < 4; u++) {
            float dtv = dt4[u];
            float xv  = xv4[u];
            S += dtv;
            float cm = dtv * xv;
            const float* br = lb + (tb + u) * Nr;
            float4 b0 = *(const float4*)(br);
            float4 b1 = *(const float4*)(br + 4);
            float4 b2 = *(const float4*)(br + 8);
            float4 b3 = *(const float4*)(br + 12);
            h[0]  = __expf(dtv*ac[0])  * h[0]  + cm * b0.x;
            h[1]  = __expf(dtv*ac[1])  * h[1]  + cm * b0.y;
            h[2]  = __expf(dtv*ac[2])  * h[2]  + cm * b0.z;
            h[3]  = __expf(dtv*ac[3])  * h[3]  + cm * b0.w;
            h[4]  = __expf(dtv*ac[4])  * h[4]  + cm * b1.x;
            h[5]  = __expf(dtv*ac[5])  * h[5]  + cm * b1.y;
            h[6]  = __expf(dtv*ac[6])  * h[6]  + cm * b1.z;
            h[7]  = __expf(dtv*ac[7])  * h[7]  + cm * b1.w;
            h[8]  = __expf(dtv*ac[8])  * h[8]  + cm * b2.x;
            h[9]  = __expf(dtv*ac[9])  * h[9]  + cm * b2.y;
            h[10] = __expf(dtv*ac[10]) * h[10] + cm * b2.z;
            h[11] = __expf(dtv*ac[11]) * h[11] + cm * b2.w;
            h[12] = __expf(dtv*ac[12]) * h[12] + cm * b3.x;
            h[13] = __expf(dtv*ac[13]) * h[13] + cm * b3.y;
            h[14] = __expf(dtv*ac[14]) * h[14] + cm * b3.z;
            h[15] = __expf(dtv*ac[15]) * h[15] + cm * b3.w;
        }
    }

    size_t obase = ((size_t)(b * NCH + ch) * Nr) * Dr + d;   // [b][ch][n][d]
    #pragma unroll
    for (int n = 0; n < 16; n++) {
        Pws[obase + (size_t)n * Dr]    = __expf(S * ac[n]);
        hendws[obase + (size_t)n * Dr] = h[n];
    }
}

// ---------------- K4: combine chunk states sequentially (batch-4 prefetch) ----------------
__global__ __launch_bounds__(256) void combine_kernel(const float* __restrict__ Pws,
                                                      const float* __restrict__ hendws,
                                                      float* __restrict__ hinws) {
    int id = blockIdx.x * 256 + threadIdx.x;  // B*N*D = 32768 (layout [b][ch][n][d])
    int b  = id >> 14;
    int dn = id & 16383;                      // n*Dr + d
    size_t base = ((size_t)b * NCH) * (Nr * Dr) + dn;
    float hin = 0.f;
    for (int cb = 0; cb < NCH; cb += 4) {
        float p[4], he[4];
        #pragma unroll
        for (int u = 0; u < 4; u++) {
            size_t idx = base + (size_t)(cb + u) * (Nr * Dr);
            p[u]  = Pws[idx];
            he[u] = hendws[idx];
        }
        #pragma unroll
        for (int u = 0; u < 4; u++) {
            size_t idx = base + (size_t)(cb + u) * (Nr * Dr);
            hinws[idx] = hin;
            hin = p[u] * hin + he[u];
        }
    }
}

// ---------------- K5: scan pass 2 (re-scan with h_in; emit y + D*residual) ----------------
__global__ __launch_bounds__(256) void scan2_kernel(const float* __restrict__ dt,
                                                    const unsigned short* __restrict__ xnb,
                                                    const float* __restrict__ bin,
                                                    const float* __restrict__ cin,
                                                    const float* __restrict__ A_log,
                                                    const float* __restrict__ hinws,
                                                    const float* __restrict__ x,
                                                    const float* __restrict__ Dp,
                                                    float* __restrict__ out) {
    int d  = blockIdx.x * 256 + threadIdx.x;
    int ch = blockIdx.y;
    int b  = blockIdx.z;
    int l0 = ch * CHUNK;
    size_t rowbase = (size_t)b * Lr + l0;

    float ac[16];
    #pragma unroll
    for (int i = 0; i < 4; i++) {
        float4 t = ((const float4*)(A_log + (size_t)d * Nr))[i];
        ac[i*4+0] = -__expf(t.x);
        ac[i*4+1] = -__expf(t.y);
        ac[i*4+2] = -__expf(t.z);
        ac[i*4+3] = -__expf(t.w);
    }

    __shared__ float lb[CHUNK * Nr];
    __shared__ float lc[CHUNK * Nr];
    for (int i = threadIdx.x; i < CHUNK * Nr; i += 256) {
        lb[i] = bin[rowbase * Nr + i];
        lc[i] = cin[rowbase * Nr + i];
    }
    __syncthreads();

    size_t obase = ((size_t)(b * NCH + ch) * Nr) * Dr + d;   // [b][ch][n][d]
    float h[16];
    #pragma unroll
    for (int n = 0; n < 16; n++) h[n] = hinws[obase + (size_t)n * Dr];

    float dp = Dp[d];
    const float* dtp         = dt  + rowbase * Dr + d;
    const unsigned short* xp = xnb + rowbase * Dr + d;
    const float* xr          = x   + rowbase * Dr + d;
    float* op                = out + rowbase * Dr + d;

    for (int tb = 0; tb < CHUNK; tb += 4) {
        float dt4[4], xv4[4], xr4[4];
        #pragma unroll
        for (int u = 0; u < 4; u++) {
            dt4[u] = dtp[(tb + u) * Dr];
            xv4[u] = bf2f(xp[(tb + u) * Dr]);
            xr4[u] = xr[(tb + u) * Dr];
        }
        #pragma unroll
        for (int u = 0; u < 4; u++) {
            float dtv = dt4[u];
            float xv  = xv4[u];
            float cm = dtv * xv;
            const float* br = lb + (tb + u) * Nr;
            const float* cr = lc + (tb + u) * Nr;
            float4 b0 = *(const float4*)(br);
            float4 b1 = *(const float4*)(br + 4);
            float4 b2 = *(const float4*)(br + 8);
            float4 b3 = *(const float4*)(br + 12);
            float4 c0 = *(const float4*)(cr);
            float4 c1 = *(const float4*)(cr + 4);
            float4 c2 = *(const float4*)(cr + 8);
            float4 c3 = *(const float4*)(cr + 12);
            float y = 0.f;
            h[0]  = __expf(dtv*ac[0])  * h[0]  + cm * b0.x;  y += c0.x * h[0];
            h[1]  = __expf(dtv*ac[1])  * h[1]  + cm * b0.y;  y += c0.y * h[1];
            h[2]  = __expf(dtv*ac[2])  * h[2]  + cm * b0.z;  y += c0.z * h[2];
            h[3]  = __expf(dtv*ac[3])  * h[3]  + cm * b0.w;  y += c0.w * h[3];
            h[4]  = __expf(dtv*ac[4])  * h[4]  + cm * b1.x;  y += c1.x * h[4];
            h[5]  = __expf(dtv*ac[5])  * h[5]  + cm * b1.y;  y += c1.y * h[5];
            h[6]  = __expf(dtv*ac[6])  * h[6]  + cm * b1.z;  y += c1.z * h[6];
            h[7]  = __expf(dtv*ac[7])  * h[7]  + cm * b1.w;  y += c1.w * h[7];
            h[8]  = __expf(dtv*ac[8])  * h[8]  + cm * b2.x;  y += c2.x * h[8];
            h[9]  = __expf(dtv*ac[9])  * h[9]  + cm * b2.y;  y += c2.y * h[9];
            h[10] = __expf(dtv*ac[10]) * h[10] + cm * b2.z;  y += c2.z * h[10];
            h[11] = __expf(dtv*ac[11]) * h[11] + cm * b2.w;  y += c2.w * h[11];
            h[12] = __expf(dtv*ac[12]) * h[12] + cm * b3.x;  y += c3.x * h[12];
            h[13] = __expf(dtv*ac[13]) * h[13] + cm * b3.y;  y += c3.y * h[13];
            h[14] = __expf(dtv*ac[14]) * h[14] + cm * b3.z;  y += c3.z * h[14];
            h[15] = __expf(dtv*ac[15]) * h[15] + cm * b3.w;  y += c3.w * h[15];
            op[(tb + u) * Dr] = y + dp * xr4[u];
        }
    }
}

// ---------------- host ----------------
extern "C" void kernel_launch(void* const* d_in, const int* in_sizes, int n_in,
                              void* d_out, int out_size, void* d_ws, size_t ws_size,
                              hipStream_t stream) {
    const float* x      = (const float*)d_in[0];
    const float* W_dt   = (const float*)d_in[1];
    const float* b_dt   = (const float*)d_in[2];
    const float* W_B    = (const float*)d_in[3];
    const float* W_C    = (const float*)d_in[4];
    const float* Dparam = (const float*)d_in[5];
    const float* A_log  = (const float*)d_in[6];
    const float* gamma  = (const float*)d_in[7];
    const float* beta   = (const float*)d_in[8];
    float* out = (float*)d_out;

    char* ws = (char*)d_ws;
    unsigned short* xnb  = (unsigned short*)(ws);                     // 8 MB
    unsigned short* wcat = (unsigned short*)(ws + 8388608);           // 2.125 MB
    float*          dt   = (float*)(ws + 10616832);                   // 16 MB
    float*          bin  = (float*)(ws + 27394048);                   // 256 KB
    float*          cin  = (float*)(ws + 27656192);                   // 256 KB
    float*          Pws  = (float*)(ws + 27918336);                   // 8 MB
    float*          hend = (float*)(ws + 36306944);                   // 8 MB
    float*          hin  = (float*)(ws + 44695552);                   // 8 MB  (total ~53 MB)

    ln_pack_kernel<<<M_ROWS + (NPAD * Dr) / 256, 256, 0, stream>>>(
        x, gamma, beta, xnb, W_dt, W_B, W_C, wcat);
    gemm_kernel<<<(M_ROWS / BM) * (NPAD / BN), 256, 0, stream>>>(xnb, wcat, b_dt, dt, bin, cin);
    dim3 sgrid(Dr / 256, NCH, Bsz);
    scan1_kernel<<<sgrid, 256, 0, stream>>>(dt, xnb, bin, A_log, Pws, hend);
    combine_kernel<<<(Bsz * Dr * Nr) / 256, 256, 0, stream>>>(Pws, hend, hin);
    scan2_kernel<<<sgrid, 256, 0, stream>>>(dt, xnb, bin, cin, A_log, hin, x, Dparam, out);
}